// Round 13
// baseline (214.602 us; speedup 1.0000x reference)
//
#include <hip/hip_runtime.h>
#include <cstdint>

// out[s,b,m,n] = sum_k (x+66)*0.03 * (y-160)*0.025,  S=7 B=8 M=K=N=1024
// y' = y-128; x, y' exact int8. i8 MFMA (int32-exact):
//   out = 7.5e-4 * ( S' - 32*Rx[m] + 66*Cy[n] - 10813440 ),  S' = sum x*y'
// GEMM: 256x256, 8 waves (2Mx4N), BK=64B.
//   A: global_load_lds -> 4-deep LDS ring (64KB), XOR swizzle key=(row>>1)&3.
//   B: DIRECT global->register (yt is L2-resident; col*1024+k per-lane addr is
//      the exact MFMA B-fragment; BK=64B = 1 cache line/col, no overfetch).
//   MFMA:ds_read = 16:8 per wave-tile (was 1:1 -> LDS-pipe-bound; now 2:1).
//   One raw s_barrier + counted vmcnt(2) per K-step; issue order pinned by
//   sched_barrier(0) so the vmcnt count is exact.

#define NG 56

typedef int v4i  __attribute__((ext_vector_type(4)));
typedef int v16i __attribute__((ext_vector_type(16)));

#define GLOAD16(g, l) __builtin_amdgcn_global_load_lds( \
    (const __attribute__((address_space(1))) void*)(g), \
    (__attribute__((address_space(3))) void*)(l), 16, 0, 0)

#define MFMA_I8(a, b, c) __builtin_amdgcn_mfma_i32_32x32x32_i8(a, b, c, 0, 0, 0)

typedef __attribute__((address_space(3))) const unsigned char* lds_cptr;

__device__ __forceinline__ v4i lds_read16(lds_cptr p) {
    v4i d;
    asm volatile("ds_read_b128 %0, %1" : "=v"(d) : "v"(p));
    return d;
}

__device__ __forceinline__ unsigned pack4(float4 v, float& s) {
    s += (v.x + v.y) + (v.z + v.w);
    unsigned b0 = __float_as_uint(v.x + 8388736.0f);  // 2^23 + 128
    unsigned b1 = __float_as_uint(v.y + 8388736.0f);
    unsigned b2 = __float_as_uint(v.z + 8388736.0f);
    unsigned b3 = __float_as_uint(v.w + 8388736.0f);
    return ((b0 & 0xFFu) | ((b1 & 0xFFu) << 8) | ((b2 & 0xFFu) << 16) | ((b3 & 0xFFu) << 24))
           ^ 0x80808080u;
}

// ---- prepass 1: x -> i8 + row sums ----
__global__ __launch_bounds__(256) void k_prep_x(const float* __restrict__ x,
                                                unsigned char* __restrict__ xb,
                                                float* __restrict__ rx) {
    int row  = blockIdx.x * 4 + (threadIdx.x >> 6);
    int lane = threadIdx.x & 63;
    const float* src = x + (size_t)row * 1024;
    float s = 0.f;
#pragma unroll
    for (int it = 0; it < 4; ++it) {
        float4 v = *(const float4*)(src + it * 256 + lane * 4);
        unsigned p = pack4(v, s);
        *(unsigned*)&xb[(size_t)row * 1024 + it * 256 + lane * 4] = p;
    }
#pragma unroll
    for (int off = 32; off > 0; off >>= 1) s += __shfl_down(s, off);
    if (lane == 0) rx[row] = s;
}

// ---- prepass 2: y [b][k][n] -> yt [b][n][k] i8 (= y-128), + col sums Cy ----
__global__ __launch_bounds__(256) void k_prep_y(const float* __restrict__ y,
                                                unsigned char* __restrict__ yt,
                                                float* __restrict__ cy) {
    __shared__ float tile[64][65];
    __shared__ float csum[4][64];
    int b  = blockIdx.x >> 8;
    int t  = blockIdx.x & 255;
    int kt = (t >> 4) * 64, nt = (t & 15) * 64;
    int tx = threadIdx.x & 63;
    int ty = threadIdx.x >> 6;
    const float* src = y + ((size_t)b << 20) + (size_t)kt * 1024 + nt;
    float part = 0.f;
#pragma unroll
    for (int r = 0; r < 16; ++r) {
        int kk = r * 4 + ty;
        float v = src[(size_t)kk * 1024 + tx];
        tile[kk][tx] = v;
        part += v;
    }
    csum[ty][tx] = part;
    __syncthreads();
    if (threadIdx.x < 64) {
        float s = csum[0][tx] + csum[1][tx] + csum[2][tx] + csum[3][tx];
        atomicAdd(&cy[b * 1024 + nt + tx], s);
    }
    int ky = threadIdx.x & 15;
    int ny = threadIdx.x >> 4;
#pragma unroll
    for (int r = 0; r < 4; ++r) {
        int nn = r * 16 + ny;
        unsigned b0 = __float_as_uint(tile[ky * 4 + 0][nn] + 8388608.0f);
        unsigned b1 = __float_as_uint(tile[ky * 4 + 1][nn] + 8388608.0f);
        unsigned b2 = __float_as_uint(tile[ky * 4 + 2][nn] + 8388608.0f);
        unsigned b3 = __float_as_uint(tile[ky * 4 + 3][nn] + 8388608.0f);
        unsigned p = ((b0 & 0xFFu) | ((b1 & 0xFFu) << 8) | ((b2 & 0xFFu) << 16) |
                      ((b3 & 0xFFu) << 24)) ^ 0x80808080u;
        *(unsigned*)&yt[((size_t)b << 20) + (size_t)(nt + nn) * 1024 + kt + ky * 4] = p;
    }
}

// ---- GEMM: 256x256, 8 waves, A via LDS ring-4, B direct-to-reg, i8 MFMA ----
__global__ __launch_bounds__(512, 2) void k_gemm(const unsigned char* __restrict__ xb,
                                                 const unsigned char* __restrict__ yt,
                                                 const float* __restrict__ rx,
                                                 const float* __restrict__ cy,
                                                 float* __restrict__ out) {
    __shared__ __align__(16) unsigned char As[4][256 * 64];   // 64 KB, A only

    int bid = blockIdx.x;                         // 896 = 8 * 112, bijective
    int wg  = (bid & 7) * 112 + (bid >> 3);
    int g   = wg >> 4;
    int t   = wg & 15;
    int m0  = (t >> 2) * 256, n0 = (t & 3) * 256;
    int b   = g & 7;

    int tid = threadIdx.x, lane = tid & 63, w = tid >> 6;
    int wm = w >> 2, wn = w & 3;                  // 2M x 4N wave grid

    const unsigned char* Ab = xb + (size_t)g * 1048576 + (size_t)m0 * 1024;

    // A staging (verified): chunk cid -> LDS row cid>>2, phys chunk cid&3;
    // LDS (row,c) holds global (row, c ^ ((row>>1)&3)); linear dest.
    int srow   = tid >> 2;                        // 0..127 (g0); +128 (g1)
    int schunk = (tid & 3) ^ ((srow >> 1) & 3);
    size_t offA0 = (size_t)srow * 1024 + (size_t)schunk * 16;
    size_t offA1 = offA0 + 131072;                // rows +128, same key
    int dstA0 = (tid & ~63) * 16;
    int dstA1 = 8192 + (tid & ~63) * 16;

#define STAGE(buf, kbyte) do {                                    \
    GLOAD16(Ab + offA0 + (size_t)(kbyte), &As[buf][dstA0]);       \
    GLOAD16(Ab + offA1 + (size_t)(kbyte), &As[buf][dstA1]);       \
} while (0)

    v16i acc[4][2];
#pragma unroll
    for (int i = 0; i < 4; ++i)
#pragma unroll
        for (int j = 0; j < 2; ++j)
#pragma unroll
            for (int q = 0; q < 16; ++q) acc[i][j][q] = 0;

    // A fragment addresses (verified): row = wm*128 + fi*32 + (lane&31)
    int arow = lane & 31, hi = lane >> 5, key = (lane >> 1) & 3;
    int rA0 = (wm * 128 +  0 + arow) * 64;
    int rA1 = (wm * 128 + 32 + arow) * 64;
    int rA2 = (wm * 128 + 64 + arow) * 64;
    int rA3 = (wm * 128 + 96 + arow) * 64;
    int c0 = (hi ^ key) * 16;          // kk=0
    int c1 = ((2 + hi) ^ key) * 16;    // kk=1

    // B direct-load per-lane base: col = n0 + wn*64 + fj*32 + (lane&31);
    // byte = col*1024 + t*64 + kk*32 + hi*16  (same fragment map verified R1-R8)
    const unsigned char* Bbl = yt + ((size_t)b << 20)
                             + (size_t)(n0 + wn * 64 + arow) * 1024 + hi * 16;

#define LOADB(R0, R1, R2, R3, kbyte) do {                                             \
    const unsigned char* _bp = Bbl + (size_t)(kbyte);                                 \
    asm volatile("global_load_dwordx4 %0, %1, off" : "=&v"(R0) : "v"(_bp) : "memory");          \
    asm volatile("global_load_dwordx4 %0, %1, off" : "=&v"(R1) : "v"(_bp + 32) : "memory");     \
    asm volatile("global_load_dwordx4 %0, %1, off" : "=&v"(R2) : "v"(_bp + 32768) : "memory");  \
    asm volatile("global_load_dwordx4 %0, %1, off" : "=&v"(R3) : "v"(_bp + 32800) : "memory");  \
} while (0)

// one K-step: wait(B(T),A(T)) -> barrier -> 8 ds_read A -> load B(T+1) ->
// stage A(T+3) -> lgkm(0) -> 16 MFMA with B(T) regs.
// BU*: B(T) regs (kk0fj0, kk1fj0, kk0fj1, kk1fj1); BL*: dest for B(T+1).
#define STEP(T, VMN, BU0, BU1, BU2, BU3, BL0, BL1, BL2, BL3, DOLB, DOST) do { \
    asm volatile("s_waitcnt vmcnt(" #VMN ")" ::: "memory");                   \
    __builtin_amdgcn_s_barrier();                                             \
    __builtin_amdgcn_sched_barrier(0);                                        \
    lds_cptr _ap = (lds_cptr)&As[(T) & 3][0];                                 \
    v4i a00 = lds_read16(_ap + rA0 + c0);                                     \
    v4i a10 = lds_read16(_ap + rA1 + c0);                                     \
    v4i a20 = lds_read16(_ap + rA2 + c0);                                     \
    v4i a30 = lds_read16(_ap + rA3 + c0);                                     \
    v4i a01 = lds_read16(_ap + rA0 + c1);                                     \
    v4i a11 = lds_read16(_ap + rA1 + c1);                                     \
    v4i a21 = lds_read16(_ap + rA2 + c1);                                     \
    v4i a31 = lds_read16(_ap + rA3 + c1);                                     \
    if (DOLB) { LOADB(BL0, BL1, BL2, BL3, ((T) + 1) * 64); }                  \
    __builtin_amdgcn_sched_barrier(0);                                        \
    if (DOST) { STAGE(((T) + 3) & 3, ((T) + 3) * 64); }                       \
    __builtin_amdgcn_sched_barrier(0);                                        \
    asm volatile("s_waitcnt lgkmcnt(0)" ::: "memory");                        \
    __builtin_amdgcn_sched_barrier(0);                                        \
    __builtin_amdgcn_s_setprio(1);                                            \
    acc[0][0] = MFMA_I8(a00, BU0, acc[0][0]);                                 \
    acc[1][0] = MFMA_I8(a10, BU0, acc[1][0]);                                 \
    acc[2][0] = MFMA_I8(a20, BU0, acc[2][0]);                                 \
    acc[3][0] = MFMA_I8(a30, BU0, acc[3][0]);                                 \
    acc[0][1] = MFMA_I8(a00, BU2, acc[0][1]);                                 \
    acc[1][1] = MFMA_I8(a10, BU2, acc[1][1]);                                 \
    acc[2][1] = MFMA_I8(a20, BU2, acc[2][1]);                                 \
    acc[3][1] = MFMA_I8(a30, BU2, acc[3][1]);                                 \
    acc[0][0] = MFMA_I8(a01, BU1, acc[0][0]);                                 \
    acc[1][0] = MFMA_I8(a11, BU1, acc[1][0]);                                 \
    acc[2][0] = MFMA_I8(a21, BU1, acc[2][0]);                                 \
    acc[3][0] = MFMA_I8(a31, BU1, acc[3][0]);                                 \
    acc[0][1] = MFMA_I8(a01, BU3, acc[0][1]);                                 \
    acc[1][1] = MFMA_I8(a11, BU3, acc[1][1]);                                 \
    acc[2][1] = MFMA_I8(a21, BU3, acc[2][1]);                                 \
    acc[3][1] = MFMA_I8(a31, BU3, acc[3][1]);                                 \
    __builtin_amdgcn_s_setprio(0);                                            \
} while (0)

    v4i bA0, bA1, bA2, bA3;   // B regs used on even steps
    v4i bB0, bB1, bB2, bB3;   // B regs used on odd steps

    // prologue (issue order pinned): A(0), A(1), B(0), A(2)
    STAGE(0, 0);
    STAGE(1, 64);
    __builtin_amdgcn_sched_barrier(0);
    LOADB(bA0, bA1, bA2, bA3, 0);
    __builtin_amdgcn_sched_barrier(0);
    STAGE(2, 128);
    __builtin_amdgcn_sched_barrier(0);

    // steady state T=0..13: entering in-flight = [A(T+1)x2, B(T)x4, A(T+2)x2]
    // -> vmcnt(2) drains through B(T). Steps issue B(T+1) then A(T+3).
#pragma unroll 1
    for (int T = 0; T < 14; T += 2) {
        STEP(T,     2, bA0, bA1, bA2, bA3, bB0, bB1, bB2, bB3, 1, (T < 13));
        STEP(T + 1, 2, bB0, bB1, bB2, bB3, bA0, bA1, bA2, bA3, 1, (T + 1 < 13));
    }
    // T=14: in-flight [A(15)x2, B(14)x4] -> vmcnt(0); loads B(15)
    STEP(14, 0, bA0, bA1, bA2, bA3, bB0, bB1, bB2, bB3, 1, 0);
    // T=15: in-flight [B(15)x4] -> vmcnt(0); no loads
    STEP(15, 0, bB0, bB1, bB2, bB3, bA0, bA1, bA2, bA3, 0, 0);
#undef STEP
#undef LOADB
#undef STAGE

    // epilogue: out = 7.5e-4 * (S' - 32*Rx + 66*Cy - 10813440)
    // C/D layout: col = lane&31, row = (q&3) + 8*(q>>2) + 4*(lane>>5)
    const float* rxp = rx + g * 1024 + m0 + wm * 128;
    const float* cyp = cy + b * 1024 + n0 + wn * 64;
    float* og = out + (size_t)g * 1048576 + (size_t)(m0 + wm * 128) * 1024 + n0 + wn * 64;
    int col = lane & 31, r4 = hi * 4;
#pragma unroll
    for (int fi = 0; fi < 4; ++fi)
#pragma unroll
        for (int fj = 0; fj < 2; ++fj) {
            int cc = fj * 32 + col;
            float cv = cyp[cc];
            v16i v = acc[fi][fj];
#pragma unroll
            for (int q = 0; q < 16; ++q) {
                int rl = (q & 3) + 8 * (q >> 2) + r4;
                float rxv = rxp[fi * 32 + rl];
                og[(size_t)(fi * 32 + rl) * 1024 + cc] =
                    7.5e-4f * ((float)v[q] - 32.0f * rxv + 66.0f * cv - 10813440.0f);
            }
        }
}

// ---- emergency fallback ----
__global__ void k_naive(const float* __restrict__ x, const float* __restrict__ y,
                        float* __restrict__ out) {
    int g = blockIdx.z, b = g & 7;
    int tx = threadIdx.x, ty = threadIdx.y;
    int m = blockIdx.y * 16 + ty, n = blockIdx.x * 16 + tx;
    __shared__ float a[16][17], bs[16][17];
    float s = 0.f;
    for (int kt = 0; kt < 64; ++kt) {
        a[ty][tx]  = x[(size_t)g * 1048576 + (size_t)m * 1024 + kt * 16 + tx];
        bs[ty][tx] = y[(size_t)b * 1048576 + (size_t)(kt * 16 + ty) * 1024 + n];
        __syncthreads();
#pragma unroll
        for (int j = 0; j < 16; ++j)
            s += ((a[ty][j] + 66.0f) * 0.03f) * ((bs[j][tx] - 160.0f) * 0.025f);
        __syncthreads();
    }
    out[(size_t)g * 1048576 + (size_t)m * 1024 + n] = s;
}

extern "C" void kernel_launch(void* const* d_in, const int* in_sizes, int n_in,
                              void* d_out, int out_size, void* d_ws, size_t ws_size,
                              hipStream_t stream) {
    const float* x = (const float*)d_in[0];
    const float* y = (const float*)d_in[1];
    float* out = (float*)d_out;

    const size_t CY_OFF = 0;                         // 32 KB
    const size_t RX_OFF = 32768;                     // 224 KB
    const size_t YT_OFF = 262144;                    // 8 MB
    const size_t XB_OFF = 262144 + 8388608ull;       // 56 MB
    const size_t NEED   = XB_OFF + 58720256ull;

    if (ws_size >= NEED) {
        float* cy         = (float*)((char*)d_ws + CY_OFF);
        float* rx         = (float*)((char*)d_ws + RX_OFF);
        unsigned char* yt = (unsigned char*)((char*)d_ws + YT_OFF);
        unsigned char* xb = (unsigned char*)((char*)d_ws + XB_OFF);
        hipMemsetAsync(cy, 0, 32768, stream);
        k_prep_x<<<14336, 256, 0, stream>>>(x, xb, rx);
        k_prep_y<<<2048, 256, 0, stream>>>(y, yt, cy);
        k_gemm<<<NG * 16, 512, 0, stream>>>(xb, yt, rx, cy, out);
    } else {
        dim3 grid(64, 64, NG), blk(16, 16);
        k_naive<<<grid, blk, 0, stream>>>(x, y, out);
    }
}